// Round 1
// baseline (142.274 us; speedup 1.0000x reference)
//
#include <hip/hip_runtime.h>
#include <stdint.h>

typedef _Float16 half8  __attribute__((ext_vector_type(8)));
typedef float    f32x4  __attribute__((ext_vector_type(4)));
typedef uint32_t u32x4  __attribute__((ext_vector_type(4)));

#define FIN  288
#define NOUT 64
#define LPB  3844            // 62*62
#define KSPL 72
#define NBF  20736           // bfrag half8 slots (331,776 B)
#define NBAS (16*64*32*64)   // basis half8 slots (33.5 MB), layout [b][h][cperm][w]

// base-part LDS tile: channel stride SC floats + (c>>3)*8 skew so the
// K-permuted base reads (addr = (q*8+j)*SC + q*8 + ...) land 2-way/bank (free).
#define SC   200
#define LDSN 6432            // max idx 31*200+24+128+65 = 6417, padded

// legacy LDS size (fallback path, byte-identical to the verified kernel)
#define LDSL (31*SC + 2*64 + 64 + 8)

// K-order (spline): kt = ii*24 + jj*8 + g, quad q -> channel c = 4g+q,
// feature f = 9c + 3ii + jj.  cperm = (c&3)*8 + (c>>2) = q*8 + g, so the
// A-fragment for (ii,jj,g) is ONE dwordx4 from bas[(b,ho+ii,q*8+g,wo+jj)].
// K-order (base): k8 = q*8+j -> feature f = 9*k8 + (3*i2+j2), (i2,j2)=pos(kb),
// making the LDS address affine in compile-time kb (no runtime f-decode).

// ---------------- cubic B-spline basis: 8 slots, f16-packed ----------------
__device__ inline half8 bspline8(float xv) {
  float u = fmaf(xv, 2.5f, 5.5f);
  float fi = floorf(u);
  int i = (int)fi;
  float t = u - fi, s = 1.0f - t;
  float t2 = t * t, t3 = t2 * t;
  float s2 = s * s, s3 = s2 * s;
  float w3 = t3 * 0.16666667f;
  float w0 = s3 * 0.16666667f;
  float w1 = fmaf(0.5f, t3, -t2) + 0.66666667f;
  float w2 = fmaf(0.5f, s3, -s2) + 0.66666667f;
  uint32_t u01 = __builtin_bit_cast(uint32_t, __builtin_amdgcn_cvt_pkrtz(w0, w1));
  uint32_t u23 = __builtin_bit_cast(uint32_t, __builtin_amdgcn_cvt_pkrtz(w2, w3));
  uint64_t V = (uint64_t)u01 | ((uint64_t)u23 << 32);
  uint32_t vl = (uint32_t)(V << 16);
  u32x4 fr;
#pragma unroll
  for (int q = 0; q < 4; ++q) {
    int d = i - 2 * q;
    uint32_t rr = (uint32_t)(V >> ((48 - 16 * d) & 63));
    fr[q] = ((uint32_t)d <= 3u) ? rr : ((d == 4) ? vl : 0u);
  }
  return __builtin_bit_cast(half8, fr);
}

// ---------------- prep: per-element basis + weight B-fragments ----------------
__global__ __launch_bounds__(256) void prep_all(const float* __restrict__ x,
                                                const float* __restrict__ bw,
                                                const float* __restrict__ sw,
                                                const float* __restrict__ sc,
                                                half8* __restrict__ ws) {
  int bid = blockIdx.x;
  if (bid < 2048) {
    // basis: thread handles 4 consecutive w of one (b,h,cperm) row
    int t = bid * 256 + threadIdx.x;        // 0..524287
    int w4 = t & 15;
    int cperm = (t >> 4) & 31;
    int bh = t >> 9;                        // b*64 + h
    int c = ((cperm & 7) << 2) | (cperm >> 3);   // c = 4g + quad
    const float4 v = *(const float4*)(x + (bh >> 6) * 131072 + c * 4096 +
                                      (bh & 63) * 64 + w4 * 4);
    half8* dst = ws + NBF + (size_t)t * 4;  // fully linear, coalesced 64B/thread
    dst[0] = bspline8(v.x);
    dst[1] = bspline8(v.y);
    dst[2] = bspline8(v.z);
    dst[3] = bspline8(v.w);
  } else {
    int t = (bid - 2048) * 256 + threadIdx.x;   // 0..20735
    half8 v;
    int dst;
    if (t < NOUT * FIN) {                   // spline (o,f) pairs (unchanged)
      int o = t / FIN;
      int f = t - o * FIN;
      float scale = sc[t];
      const float* p = sw + t * 8;
#pragma unroll
      for (int c = 0; c < 8; ++c) v[c] = (_Float16)(p[c] * scale);
      int ch = f / 9;
      int r  = f - ch * 9;
      int ii = r / 3;
      int jj = r - ii * 3;
      int g  = ch >> 2, q = ch & 3;
      int kt = ii * 24 + jj * 8 + g;
      dst = (kt * 4 + (o >> 4)) * 64 + q * 16 + (o & 15);
    } else {                                // base frags, NEW K-permutation
      int t2 = t - NOUT * FIN;
      int lane = t2 & 63;
      int nf = (t2 >> 6) & 3;
      int ktb = t2 >> 8;                    // 0..8
      int o = nf * 16 + (lane & 15);
      int q = lane >> 4;
      int i2 = ktb / 3;
      int j2 = ktb - 3 * i2;
#pragma unroll
      for (int c0 = 0; c0 < 8; ++c0)
        v[c0] = (_Float16)bw[o * FIN + 9 * (q * 8 + c0) + 3 * i2 + j2];
      dst = ((KSPL + ktb) * 4 + nf) * 64 + lane;
    }
    ws[dst] = v;
  }
}

// ---------------- main: one (b,ho) row per block ----------------
__global__ __launch_bounds__(256, 4) void kan_main(
    const float* __restrict__ x,
    const half8* __restrict__ ws,
    float* __restrict__ out) {
  __shared__ float lx[LDSN];
  const half8* __restrict__ bfrag = ws;
  const half8* __restrict__ bas   = ws + NBF;

  const int tid = threadIdx.x;
  int bid0 = blockIdx.x;
  // XCD swizzle: 992 = 8*124, bijective; adjacent ho share 2/3 basis rows in L2
  int bid = (bid0 & 7) * 124 + (bid0 >> 3);
  const int b  = bid / 62;
  const int ho = bid - b * 62;

  // ---- stage x tile (base part only): 32 ch x 3 rows x 64 cols, skewed ----
  const float* xb = x + b * 131072 + ho * 64;
#pragma unroll
  for (int r = 0; r < 6; ++r) {
    int gid = r * 256 + tid;
    int row = gid >> 4;                 // c*3+ii
    int c   = (row * 683) >> 11;        // row/3
    int ii  = row - c * 3;
    int colv = (gid & 15) * 4;
    const float4 v = *(const float4*)(xb + c * 4096 + ii * 64 + colv);
    *(float4*)(&lx[c * SC + (c >> 3) * 8 + ii * 64 + colv]) = v;
  }
  // no barrier yet: spline section doesn't touch LDS; staging hides under MFMAs

  const int lane = tid & 63;
  const int wv   = tid >> 6;
  const int quad = lane >> 4;
  const int m16  = lane & 15;
  const int wo   = wv * 16 + m16;       // 0..63 (>=62 lanes: garbage, not stored)

  f32x4 acc[4];
#pragma unroll
  for (int nf = 0; nf < 4; ++nf) acc[nf] = (f32x4){0.f, 0.f, 0.f, 0.f};

  // ---- spline K-slices: A-fragment = one dwordx4 from precomputed basis ----
  const half8* bb = bas + (size_t)((b * 64 + ho) * 32 + quad * 8) * 64 + wo;
  int kt = 0;
#pragma unroll
  for (int ii = 0; ii < 3; ++ii) {
#pragma unroll
    for (int jj = 0; jj < 3; ++jj) {
      const half8* p = bb + ii * 2048 + jj;
#pragma unroll
      for (int g = 0; g < 8; ++g) {
        half8 af = p[g * 64];
#pragma unroll
        for (int nf = 0; nf < 4; ++nf) {
          half8 bf = bfrag[(kt * 4 + nf) * 64 + lane];
          acc[nf] = __builtin_amdgcn_mfma_f32_16x16x32_f16(af, bf, acc[nf], 0, 0, 0);
        }
        ++kt;
      }
    }
  }

  __syncthreads();   // staging stores complete before base reads

  // ---- base K-slices: f = 9*k8 + pos(kb); addresses affine in kb ----
  const float* lb = lx + quad * (8 * SC) + quad * 8 + wo;
#pragma unroll
  for (int kb = 0; kb < 9; ++kb) {
    const int i2 = kb / 3;
    const int j2 = kb - 3 * i2;
    half8 a;
#pragma unroll
    for (int j = 0; j < 8; ++j)
      a[j] = (_Float16)fmaxf(lb[j * SC + i2 * 64 + j2], 0.0f);
#pragma unroll
    for (int nf = 0; nf < 4; ++nf) {
      half8 bf = bfrag[((KSPL + kb) * 4 + nf) * 64 + lane];
      acc[nf] = __builtin_amdgcn_mfma_f32_16x16x32_f16(a, bf, acc[nf], 0, 0, 0);
    }
  }

  // ---- epilogue: col(=out)=m16, row(=pixel)=quad*4+reg ----
  float* ob = out + b * (NOUT * LPB) + ho * 62;
#pragma unroll
  for (int rg = 0; rg < 4; ++rg) {
    int wo2 = wv * 16 + quad * 4 + rg;
    if (wo2 < 62) {
#pragma unroll
      for (int nf = 0; nf < 4; ++nf) {
        int o = nf * 16 + m16;
        ob[o * LPB + wo2] = acc[nf][rg];
      }
    }
  }
}

// ================= legacy fallback (verified kernel, verbatim) =================
__global__ void prep_bfrag_legacy(const float* __restrict__ bw,
                                  const float* __restrict__ sw,
                                  const float* __restrict__ sc,
                                  half8* __restrict__ bfrag) {
  int t = blockIdx.x * 256 + threadIdx.x;
  half8 v;
  int dst;
  if (t < NOUT * FIN) {
    int o = t / FIN;
    int f = t - o * FIN;
    float scale = sc[t];
    const float* p = sw + t * 8;
#pragma unroll
    for (int c = 0; c < 8; ++c) v[c] = (_Float16)(p[c] * scale);
    int ch = f / 9;
    int r  = f - ch * 9;
    int ii = r / 3;
    int jj = r - ii * 3;
    int g  = ch >> 2, q = ch & 3;
    int kt = ii * 24 + jj * 8 + g;
    dst = (kt * 4 + (o >> 4)) * 64 + q * 16 + (o & 15);
  } else {
    int t2 = t - NOUT * FIN;
    int lane = t2 & 63;
    int nf = (t2 >> 6) & 3;
    int ktb = t2 >> 8;
    int o = nf * 16 + (lane & 15);
    int f0 = ktb * 32 + (lane >> 4) * 8;
    const float* p = bw + o * FIN + f0;
#pragma unroll
    for (int c = 0; c < 8; ++c) v[c] = (_Float16)p[c];
    dst = ((KSPL + ktb) * 4 + nf) * 64 + lane;
  }
  bfrag[dst] = v;
}

__global__ __launch_bounds__(256, 4) void kan_main_legacy(
    const float* __restrict__ x,
    const half8* __restrict__ bfrag,
    float* __restrict__ out) {
  __shared__ float lx[LDSL];
  const int tid = threadIdx.x;
  const int bid = blockIdx.x;
  const int b  = bid / 62;
  const int ho = bid - b * 62;
  const float* xb = x + b * 131072 + ho * 64;
#pragma unroll
  for (int r = 0; r < 6; ++r) {
    int gid = r * 256 + tid;
    int row = gid >> 4;
    int c   = (row * 683) >> 11;
    int ii  = row - c * 3;
    int colv = (gid & 15) * 4;
    const float4 v = *(const float4*)(xb + c * 4096 + ii * 64 + colv);
    *(float4*)(&lx[c * SC + ii * 64 + colv]) = v;
  }
  __syncthreads();
  const int lane = tid & 63;
  const int wv   = tid >> 6;
  const int quad = lane >> 4;
  const int m16  = lane & 15;
  const int wo   = wv * 16 + m16;
  f32x4 acc[4];
#pragma unroll
  for (int nf = 0; nf < 4; ++nf) acc[nf] = (f32x4){0.f, 0.f, 0.f, 0.f};
  int kt = 0;
#pragma unroll
  for (int ii = 0; ii < 3; ++ii) {
#pragma unroll
    for (int jj = 0; jj < 3; ++jj) {
      const float* lbase = lx + quad * SC + ii * 64 + wo + jj;
#pragma unroll
      for (int g = 0; g < 8; ++g) {
        float xv = lbase[g * (4 * SC)];
        half8 af = bspline8(xv);
#pragma unroll
        for (int nf = 0; nf < 4; ++nf) {
          half8 bf = bfrag[(kt * 4 + nf) * 64 + lane];
          acc[nf] = __builtin_amdgcn_mfma_f32_16x16x32_f16(af, bf, acc[nf], 0, 0, 0);
        }
        ++kt;
      }
    }
  }
#pragma unroll
  for (int kb = 0; kb < 9; ++kb) {
    int f0 = kb * 32 + quad * 8;
    half8 a;
#pragma unroll
    for (int j = 0; j < 8; ++j) {
      int f = f0 + j;
      int c = (f * 57) >> 9;
      int r = f - c * 9;
      int i2 = (r * 11) >> 5;
      int j2 = r - i2 * 3;
      a[j] = (_Float16)fmaxf(lx[c * SC + i2 * 64 + wo + j2], 0.0f);
    }
#pragma unroll
    for (int nf = 0; nf < 4; ++nf) {
      half8 bf = bfrag[((KSPL + kb) * 4 + nf) * 64 + lane];
      acc[nf] = __builtin_amdgcn_mfma_f32_16x16x32_f16(a, bf, acc[nf], 0, 0, 0);
    }
  }
  float* ob = out + b * (NOUT * LPB) + ho * 62;
#pragma unroll
  for (int rg = 0; rg < 4; ++rg) {
    int wo2 = wv * 16 + quad * 4 + rg;
    if (wo2 < 62) {
#pragma unroll
      for (int nf = 0; nf < 4; ++nf) {
        int o = nf * 16 + m16;
        ob[o * LPB + wo2] = acc[nf][rg];
      }
    }
  }
}

extern "C" void kernel_launch(void* const* d_in, const int* in_sizes, int n_in,
                              void* d_out, int out_size, void* d_ws, size_t ws_size,
                              hipStream_t stream) {
  const float* x  = (const float*)d_in[0];
  const float* bw = (const float*)d_in[1];  // (64, 288)
  const float* sw = (const float*)d_in[2];  // (64, 288, 8)
  const float* sc = (const float*)d_in[3];  // (64, 288)
  float* out = (float*)d_out;
  half8* ws = (half8*)d_ws;

  const size_t need = (size_t)(NBF + NBAS) * sizeof(half8);  // 33,886,208 B
  if (ws_size >= need) {
    prep_all<<<2048 + 81, 256, 0, stream>>>(x, bw, sw, sc, ws);
    kan_main<<<16 * 62, 256, 0, stream>>>(x, ws, out);
  } else {
    prep_bfrag_legacy<<<81, 256, 0, stream>>>(bw, sw, sc, ws);
    kan_main_legacy<<<16 * 62, 256, 0, stream>>>(x, ws, out);
  }
}